// Round 8
// baseline (620.416 us; speedup 1.0000x reference)
//
#include <hip/hip_runtime.h>
#include <stdint.h>

#define D 128
#define MT 32
#define HS 136          // H row stride in shorts (17*16B, 0 conflicts measured)

typedef short short8 __attribute__((ext_vector_type(8)));
typedef float f32x16 __attribute__((ext_vector_type(16)));

__device__ __forceinline__ unsigned short f2bf(float f) {
    union { float f; uint32_t u; } v;
    v.f = f;
    uint32_t u = v.u;
    uint32_t r = (u + 0x7fffu + ((u >> 16) & 1u)) >> 16;  // RNE
    return (unsigned short)r;
}

// Pack W1 (384x128) / W2 (128x128) fp32 row-major -> bf16 MFMA-B fragment order:
// frag index ((kt*4 + nt)*64 + lane)*8 + j holds W[k = kt*16 + (lane>>5)*8 + j][n = nt*32 + (lane&31)]
__global__ void pack_weights_kernel(const float* __restrict__ W1,
                                    const float* __restrict__ W2,
                                    unsigned short* __restrict__ W1p,
                                    unsigned short* __restrict__ W2p) {
    int t = blockIdx.x * 256 + threadIdx.x;
    if (t < 6144) {               // W1: 24 ksteps * 4 colblocks * 64 lanes
        int kt = t >> 8, nt = (t >> 6) & 3, lane = t & 63;
        int n = nt * 32 + (lane & 31);
        int kb = kt * 16 + (lane >> 5) * 8;
        unsigned short* dst = W1p + t * 8;
        #pragma unroll
        for (int j = 0; j < 8; ++j) dst[j] = f2bf(W1[(kb + j) * D + n]);
    } else if (t < 8192) {        // W2: 8 ksteps * 4 colblocks * 64 lanes
        int u = t - 6144;
        int kt = u >> 8, nt = (u >> 6) & 3, lane = u & 63;
        int n = nt * 32 + (lane & 31);
        int kb = kt * 16 + (lane >> 5) * 8;
        unsigned short* dst = W2p + u * 8;
        #pragma unroll
        for (int j = 0; j < 8; ++j) dst[j] = f2bf(W2[(kb + j) * D + n]);
    }
}

// 32 edges/block, 256 threads = 4 waves (wave w owns output cols [32w,32w+32)).
// Register-free staging: X_cat staged as fp32 via 48x global_load_lds(16B) in
// MFMA-fragment order — chunk(kt,jj) is 1024B at Af+(kt*2+jj)*1024; lane l's 16B
// = X[row l&31][k = kt*16+(l>>5)*8+jj*4 ..+3]. Global src is per-lane (gathered
// row), LDS dest linear (wave-uniform base + lane*16) -> reads are conflict-free
// ds_read_b128, zero VGPR payload, 48KB outstanding per staging block (vs ~7KB
// with register staging = the 2.9TB/s cap of R0-R6). f32->bf16 conversion moves
// to the GEMM1 fragment read (scalar f2bf; compiler schedules — m240).
// LDS 48KB, H bf16 aliased (barrier-separated) -> 3 blocks/CU.
__global__ __launch_bounds__(256, 3) void edge_mlp_kernel(
    const float* __restrict__ x_node,
    const float* __restrict__ x_edge,
    const int* __restrict__ eidx,
    const unsigned short* __restrict__ W1p,
    const unsigned short* __restrict__ W2p,
    const float* __restrict__ b1,
    const float* __restrict__ b2,
    float* __restrict__ out,
    int E) {
    __shared__ float Af[12288];                  // 48 KB: 48 chunks of 1024 B
    unsigned short* Hs = (unsigned short*)Af;    // aliased, barrier-separated

    const int t = threadIdx.x;
    const int r0 = blockIdx.x * MT;

    const int w = t >> 6;                 // wave 0..3 -> column block / stage slice
    const int l = t & 63;
    const int lrow = l & 31;
    const int hi = l >> 5;                // 0/1
    const int khalf = hi * 8;
    const int n = w * 32 + lrow;
    const int rbump = hi * 4;

    // ---- per-lane gather bases: one int2 eidx load per lane ----
    const int row = r0 + lrow;
    const int rc = row < E ? row : E - 1;
    const int2 el = ((const int2*)eidx)[rc];
    const float* g0 = x_node + (size_t)el.x * D + hi * 8;   // v0 row, this lane's k-half
    const float* g1 = x_node + (size_t)el.y * D + hi * 8;   // v1 row
    const float* g2 = x_edge + (size_t)rc * D + hi * 8;     // v2 row

    // ---- stage: 12 global_load_lds(16B) per wave, zero VGPR payload ----
    #pragma unroll
    for (int i = 0; i < 6; ++i) {
        const int kt = w * 6 + i;                           // wave-uniform 0..23
        const float* gb = (kt < 8 ? g0 : (kt < 16 ? g1 : g2)) + (kt & 7) * 16;
        float* ld = Af + kt * 512;                          // wave-uniform LDS dest
        __builtin_amdgcn_global_load_lds(
            (const __attribute__((address_space(1))) void*)(gb),
            (__attribute__((address_space(3))) void*)(ld), 16, 0, 0);
        __builtin_amdgcn_global_load_lds(
            (const __attribute__((address_space(1))) void*)(gb + 4),
            (__attribute__((address_space(3))) void*)(ld + 256), 16, 0, 0);
    }
    asm volatile("s_waitcnt vmcnt(0)" ::: "memory");
    __syncthreads();

    // ---- GEMM1: H = relu(X_cat @ W1 + b1), K = 384; cvt f32->bf16 at read ----
    f32x16 acc;
    #pragma unroll
    for (int i = 0; i < 16; ++i) acc[i] = 0.f;

    #pragma unroll
    for (int kt = 0; kt < 24; ++kt) {
        float4 fa0 = *(const float4*)(Af + kt * 512 + l * 4);         // conflict-free
        float4 fa1 = *(const float4*)(Af + kt * 512 + 256 + l * 4);   // conflict-free
        union { short8 s; ushort4 h[2]; } av;
        av.h[0].x = f2bf(fa0.x); av.h[0].y = f2bf(fa0.y);
        av.h[0].z = f2bf(fa0.z); av.h[0].w = f2bf(fa0.w);
        av.h[1].x = f2bf(fa1.x); av.h[1].y = f2bf(fa1.y);
        av.h[1].z = f2bf(fa1.z); av.h[1].w = f2bf(fa1.w);
        short8 b = *(const short8*)(W1p + ((kt * 4 + w) * 64 + l) * 8);
        acc = __builtin_amdgcn_mfma_f32_32x32x16_bf16(av.s, b, acc, 0, 0, 0);
    }
    __syncthreads();   // all waves done reading Af before H overwrites it

    {
        float b1v = b1[n];
        #pragma unroll
        for (int r = 0; r < 16; ++r) {
            int rr = (r & 3) + 8 * (r >> 2) + rbump;   // C-layout row within tile
            Hs[rr * HS + n] = f2bf(fmaxf(acc[r] + b1v, 0.f));
        }
    }
    __syncthreads();

    // ---- GEMM2: OUT = H @ W2 + b2, K = 128 ----
    f32x16 c;
    #pragma unroll
    for (int i = 0; i < 16; ++i) c[i] = 0.f;

    #pragma unroll
    for (int kt = 0; kt < 8; ++kt) {
        short8 a = *(const short8*)&Hs[lrow * HS + kt * 16 + khalf];
        short8 b = *(const short8*)(W2p + ((kt * 4 + w) * 64 + l) * 8);
        c = __builtin_amdgcn_mfma_f32_32x32x16_bf16(a, b, c, 0, 0, 0);
    }

    {
        float b2v = b2[n];
        #pragma unroll
        for (int r = 0; r < 16; ++r) {
            int rr = (r & 3) + 8 * (r >> 2) + rbump;
            int rg = r0 + rr;
            if (rg < E) out[(size_t)rg * D + n] = c[r] + b2v;
        }
    }
}

extern "C" void kernel_launch(void* const* d_in, const int* in_sizes, int n_in,
                              void* d_out, int out_size, void* d_ws, size_t ws_size,
                              hipStream_t stream) {
    const float* x_node = (const float*)d_in[0];
    const float* x_edge = (const float*)d_in[1];
    const int*   eidx   = (const int*)d_in[2];
    const float* W1     = (const float*)d_in[3];
    const float* b1     = (const float*)d_in[4];
    const float* W2     = (const float*)d_in[5];
    const float* b2     = (const float*)d_in[6];
    float* out = (float*)d_out;

    const int E = in_sizes[1] / D;

    unsigned short* W1p = (unsigned short*)d_ws;          // 6144*8 bf16 = 96 KB
    unsigned short* W2p = W1p + 6144 * 8;                 // 2048*8 bf16 = 32 KB

    pack_weights_kernel<<<32, 256, 0, stream>>>(W1, W2, W1p, W2p);

    int nblk = (E + MT - 1) / MT;
    edge_mlp_kernel<<<nblk, 256, 0, stream>>>(x_node, x_edge, eidx, W1p, W2p, b1, b2, out, E);
}